// Round 1
// baseline (387.280 us; speedup 1.0000x reference)
//
#include <hip/hip_runtime.h>
#include <hip/hip_bf16.h>
#include <stdint.h>

// Problem constants
#define B_ 16
#define L_ 4096
#define D_ 256
#define M_ (B_*L_)   // 65536 tokens
#define N_ 768       // [loop | parent | child] concatenated output cols

typedef __attribute__((ext_vector_type(8))) short bf16x8;
typedef __attribute__((ext_vector_type(4))) float f32x4;
typedef __attribute__((ext_vector_type(4))) int i32x4;

__device__ __forceinline__ float bf2f(unsigned short u) {
  union { unsigned int i; float f; } v; v.i = ((unsigned int)u) << 16; return v.f;
}
__device__ __forceinline__ unsigned short f2bf(float f) {
  __hip_bfloat16 h = __float2bfloat16(f);
  return *reinterpret_cast<unsigned short*>(&h);
}
__device__ __forceinline__ void async16(const void* g, void* l) {
  __builtin_amdgcn_global_load_lds((const __attribute__((address_space(1))) void*)g,
                                   (__attribute__((address_space(3))) void*)l, 16, 0, 0);
}
__device__ __forceinline__ float sigmoidf_(float z) {
  return 1.f / (1.f + __expf(-z));
}

// ---------------------------------------------------------------------------
// Kernel A: per-token gate logits (f32 exact) + x -> bf16 conversion.
// One wave per token, 8 tokens per wave. Lane covers 4 cols (float4).
// ---------------------------------------------------------------------------
__global__ __launch_bounds__(256) void k_gates(
    const float* __restrict__ x, const int* __restrict__ deps,
    const float* __restrict__ wlg, const float* __restrict__ blg,
    const float* __restrict__ wcg, const float* __restrict__ bcg,
    const float* __restrict__ wpg, const float* __restrict__ bpg,
    const float* __restrict__ Epg, const float* __restrict__ Ecg,
    unsigned short* __restrict__ xb, float4* __restrict__ gates)
{
  const int lane = threadIdx.x & 63;
  const int gw = (blockIdx.x * 256 + threadIdx.x) >> 6;  // global wave id
  const float4 wl4 = ((const float4*)wlg)[lane];
  const float4 wc4 = ((const float4*)wcg)[lane];
  const float4 wp4 = ((const float4*)wpg)[lane];
  const float bl0 = blg[0], bc0 = bcg[0], bp0 = bpg[0];
  for (int t = 0; t < 8; ++t) {
    const int i = gw * 8 + t;
    float4 xv = ((const float4*)x)[(size_t)i * 64 + lane];
    float sl = xv.x * wl4.x + xv.y * wl4.y + xv.z * wl4.z + xv.w * wl4.w;
    float sc = xv.x * wc4.x + xv.y * wc4.y + xv.z * wc4.z + xv.w * wc4.w;
    float sp = xv.x * wp4.x + xv.y * wp4.y + xv.z * wp4.z + xv.w * wp4.w;
    #pragma unroll
    for (int o = 32; o; o >>= 1) {
      sl += __shfl_xor(sl, o);
      sc += __shfl_xor(sc, o);
      sp += __shfl_xor(sp, o);
    }
    ushort4 u;
    u.x = f2bf(xv.x); u.y = f2bf(xv.y); u.z = f2bf(xv.z); u.w = f2bf(xv.w);
    ((ushort4*)xb)[(size_t)i * 64 + lane] = u;
    if (lane == 0) {
      int d = deps[i];
      float gl = sigmoidf_(sl + bl0);
      float gp = sigmoidf_(sp + bp0 + Epg[d]);
      float gc = sigmoidf_(sc + bc0 + Ecg[d]);
      gates[i] = make_float4(gl, gp, gc, 0.f);
    }
  }
}

// ---------------------------------------------------------------------------
// Kernel W: build WbT [768][256] bf16 = transpose of [W_loop|W_parent|W_child]
// (B^T layout so GEMM B-fragments read contiguous along k). Tiny.
// ---------------------------------------------------------------------------
__global__ __launch_bounds__(256) void k_weights(
    const float* __restrict__ Wl, const float* __restrict__ Wp,
    const float* __restrict__ Wc, unsigned short* __restrict__ WbT)
{
  const int n = blockIdx.x;      // 0..767 output col
  const int k = threadIdx.x;     // 0..255
  const float* W = (n < 256) ? Wl : ((n < 512) ? Wp : Wc);
  const int nn = n & 255;
  WbT[(size_t)n * 256 + k] = f2bf(W[(size_t)k * 256 + nn]);
}

// ---------------------------------------------------------------------------
// Kernel B: Y[65536][768] (bf16) = xb @ Wb.  128x128 tile, 4 waves, BK=64,
// global_load_lds width-16 staging, mfma_f32_16x16x32_bf16, LDS-transpose
// epilogue for coalesced 16B stores.
// ---------------------------------------------------------------------------
__global__ __launch_bounds__(256) void k_gemm(
    const unsigned short* __restrict__ A,    // [M][256] bf16
    const unsigned short* __restrict__ Bt,   // [768][256] bf16 (N-major)
    unsigned short* __restrict__ Y)          // [M][768] bf16
{
  __shared__ unsigned short sh[2 * 128 * 64];
  unsigned short* lA = sh;
  unsigned short* lB = sh + 128 * 64;
  const int tid = threadIdx.x;
  const int wid = tid >> 6, lane = tid & 63;
  const int wm = wid >> 1, wn = wid & 1;
  const int mb = blockIdx.x, nb = blockIdx.y;

  f32x4 acc[4][4] = {};
  const unsigned short* Ag = A + (size_t)mb * 128 * 256;
  const unsigned short* Bg = Bt + (size_t)nb * 128 * 256;
  const int srow = wid * 8 + (lane >> 3);   // staging row within 32-row sweep
  const int scol = (lane & 7) * 8;          // staging col (bf16)

  for (int kb = 0; kb < 256; kb += 64) {
    #pragma unroll
    for (int s = 0; s < 4; ++s) {
      char* dA = (char*)lA + s * 4096 + wid * 1024 + lane * 16;
      char* dB = (char*)lB + s * 4096 + wid * 1024 + lane * 16;
      async16(Ag + (size_t)(s * 32 + srow) * 256 + kb + scol, dA);
      async16(Bg + (size_t)(s * 32 + srow) * 256 + kb + scol, dB);
    }
    __syncthreads();  // drains vmcnt (global_load_lds) + barrier
    #pragma unroll
    for (int kk = 0; kk < 64; kk += 32) {
      const int ko = kk + (lane >> 4) * 8;
      bf16x8 af[4], bv[4];
      #pragma unroll
      for (int m = 0; m < 4; ++m)
        af[m] = *(const bf16x8*)&lA[(wm * 64 + m * 16 + (lane & 15)) * 64 + ko];
      #pragma unroll
      for (int n = 0; n < 4; ++n)
        bv[n] = *(const bf16x8*)&lB[(wn * 64 + n * 16 + (lane & 15)) * 64 + ko];
      #pragma unroll
      for (int m = 0; m < 4; ++m)
        #pragma unroll
        for (int n = 0; n < 4; ++n)
          acc[m][n] = __builtin_amdgcn_mfma_f32_16x16x32_bf16(af[m], bv[n], acc[m][n], 0, 0, 0);
    }
    __syncthreads();  // protect LDS before next stage overwrites
  }

  // Epilogue: fragments -> LDS (bf16, [128][128]) -> coalesced 16B stores.
  #pragma unroll
  for (int m = 0; m < 4; ++m)
    #pragma unroll
    for (int n = 0; n < 4; ++n)
      #pragma unroll
      for (int r = 0; r < 4; ++r)
        sh[(wm * 64 + m * 16 + (lane >> 4) * 4 + r) * 128 + wn * 64 + n * 16 + (lane & 15)]
            = f2bf(acc[m][n][r]);
  __syncthreads();
  #pragma unroll
  for (int s = 0; s < 8; ++s) {
    const int o = s * 4096 + tid * 16;          // byte offset in 32KB tile
    const int row = o >> 8;                     // 256 B per row (128 bf16)
    const int colu = (o & 255) >> 1;            // bf16 col
    *(i32x4*)&Y[(size_t)(mb * 128 + row) * 768 + nb * 128 + colu] =
        *(const i32x4*)((const char*)sh + o);
  }
}

// ---------------------------------------------------------------------------
// Kernel C1: out[i] = mask_i * ( g_l*(Yl_i + b_loop) + g_p*(Z_{p_i} + b_parent
//            + E_pw[dep_i]) ).  Non-atomic; writes EVERY row (zeros if masked).
// ---------------------------------------------------------------------------
__global__ __launch_bounds__(256) void k_combine(
    const unsigned short* __restrict__ Y, const float4* __restrict__ gates,
    const int* __restrict__ parent, const int* __restrict__ deps,
    const int* __restrict__ mask,
    const float* __restrict__ b_loop, const float* __restrict__ b_parent,
    const float* __restrict__ Epw, float* __restrict__ out)
{
  const int lane = threadIdx.x & 63;
  const int gw = (blockIdx.x * 256 + threadIdx.x) >> 6;
  const float4 bl = ((const float4*)b_loop)[lane];
  const float4 bp = ((const float4*)b_parent)[lane];
  for (int t = 0; t < 8; ++t) {
    const int i = gw * 8 + t;
    const int b = i >> 12;
    float4 o4 = make_float4(0.f, 0.f, 0.f, 0.f);
    if (mask[i]) {
      const float4 g = gates[i];
      const int p = parent[i], d = deps[i];
      const ushort4 yl = ((const ushort4*)(Y + (size_t)i * 768))[lane];
      const ushort4 z  = ((const ushort4*)(Y + (size_t)((b << 12) + p) * 768 + 256))[lane];
      const float4 e   = ((const float4*)Epw)[d * 64 + lane];
      o4.x = g.x * (bf2f(yl.x) + bl.x) + g.y * (bf2f(z.x) + bp.x + e.x);
      o4.y = g.x * (bf2f(yl.y) + bl.y) + g.y * (bf2f(z.y) + bp.y + e.y);
      o4.z = g.x * (bf2f(yl.z) + bl.z) + g.y * (bf2f(z.z) + bp.z + e.z);
      o4.w = g.x * (bf2f(yl.w) + bl.w) + g.y * (bf2f(z.w) + bp.w + e.w);
    }
    ((float4*)out)[(size_t)i * 64 + lane] = o4;
  }
}

// ---------------------------------------------------------------------------
// Kernel C2: child scatter. dest = mask_i ? p_i : 0. Skip if mask[dest]==0
// (final masking kills it anyway). Aggregate dest==0 per-wave in registers,
// flush once (row 0 is the hot row: ~half of all tokens land there).
// ---------------------------------------------------------------------------
__global__ __launch_bounds__(256) void k_scatter(
    const unsigned short* __restrict__ Y, const float4* __restrict__ gates,
    const int* __restrict__ parent, const int* __restrict__ deps,
    const int* __restrict__ mask,
    const float* __restrict__ b_child, const float* __restrict__ Ecw,
    float* __restrict__ out)
{
  const int lane = threadIdx.x & 63;
  const int gw = (blockIdx.x * 256 + threadIdx.x) >> 6;
  const int base = gw * 16;          // 16 consecutive tokens, same batch
  const int b = base >> 12;
  const float4 bc = ((const float4*)b_child)[lane];
  const int mask0 = mask[b << 12];
  float4 a0 = make_float4(0.f, 0.f, 0.f, 0.f);
  int any0 = 0;
  for (int t = 0; t < 16; ++t) {
    const int i = base + t;
    const int mi = mask[i];
    const int p = parent[i];
    const int dest = mi ? p : 0;
    const int dm = dest ? mask[(b << 12) + dest] : mask0;
    if (!dm) continue;                           // wave-uniform branch
    const float4 g = gates[i];
    const int d = deps[i];
    const ushort4 yc = ((const ushort4*)(Y + (size_t)i * 768 + 512))[lane];
    const float4 e = ((const float4*)Ecw)[d * 64 + lane];
    float4 c;
    c.x = g.z * (bf2f(yc.x) + bc.x + e.x);
    c.y = g.z * (bf2f(yc.y) + bc.y + e.y);
    c.z = g.z * (bf2f(yc.z) + bc.z + e.z);
    c.w = g.z * (bf2f(yc.w) + bc.w + e.w);
    if (dest == 0) {
      a0.x += c.x; a0.y += c.y; a0.z += c.z; a0.w += c.w; any0 = 1;
    } else {
      float* dst = out + ((size_t)(b << 12) + dest) * 256 + lane * 4;
      unsafeAtomicAdd(dst + 0, c.x);
      unsafeAtomicAdd(dst + 1, c.y);
      unsafeAtomicAdd(dst + 2, c.z);
      unsafeAtomicAdd(dst + 3, c.w);
    }
  }
  if (any0) {
    float* dst = out + (size_t)(b << 12) * 256 + lane * 4;
    unsafeAtomicAdd(dst + 0, a0.x);
    unsafeAtomicAdd(dst + 1, a0.y);
    unsafeAtomicAdd(dst + 2, a0.z);
    unsafeAtomicAdd(dst + 3, a0.w);
  }
}

// ---------------------------------------------------------------------------
extern "C" void kernel_launch(void* const* d_in, const int* in_sizes, int n_in,
                              void* d_out, int out_size, void* d_ws, size_t ws_size,
                              hipStream_t stream) {
  const float* x        = (const float*)d_in[0];
  const int*   parent   = (const int*)d_in[1];
  const int*   deps     = (const int*)d_in[2];
  const int*   mask     = (const int*)d_in[3];
  const float* W_loop   = (const float*)d_in[4];
  const float* b_loop   = (const float*)d_in[5];
  const float* W_child  = (const float*)d_in[6];
  const float* b_child  = (const float*)d_in[7];
  const float* W_parent = (const float*)d_in[8];
  const float* b_parent = (const float*)d_in[9];
  const float* wlg      = (const float*)d_in[10];
  const float* blg      = (const float*)d_in[11];
  const float* wcg      = (const float*)d_in[12];
  const float* bcg      = (const float*)d_in[13];
  const float* wpg      = (const float*)d_in[14];
  const float* bpg      = (const float*)d_in[15];
  const float* Epw      = (const float*)d_in[16];
  const float* Ecw      = (const float*)d_in[17];
  const float* Epg      = (const float*)d_in[18];
  const float* Ecg      = (const float*)d_in[19];
  float* out = (float*)d_out;

  // Workspace layout (total ~129.4 MB)
  char* ws = (char*)d_ws;
  unsigned short* xb  = (unsigned short*)ws;                       // 32 MB
  unsigned short* WbT = (unsigned short*)(ws + 33554432);          // 384 KB
  float4* gates       = (float4*)(ws + 33554432 + 393216);         // 1 MB
  unsigned short* Yv  = (unsigned short*)(ws + 33554432 + 393216 + 1048576); // 96 MB

  k_gates<<<2048, 256, 0, stream>>>(x, deps, wlg, blg, wcg, bcg, wpg, bpg,
                                    Epg, Ecg, xb, gates);
  k_weights<<<768, 256, 0, stream>>>(W_loop, W_parent, W_child, WbT);
  dim3 gg(512, 6, 1);
  k_gemm<<<gg, 256, 0, stream>>>(xb, WbT, Yv);
  k_combine<<<2048, 256, 0, stream>>>(Yv, gates, parent, deps, mask,
                                      b_loop, b_parent, Epw, out);
  k_scatter<<<1024, 256, 0, stream>>>(Yv, gates, parent, deps, mask,
                                      b_child, Ecw, out);
}

// Round 3
// 263.838 us; speedup vs baseline: 1.4679x; 1.4679x over previous
//
#include <hip/hip_runtime.h>
#include <hip/hip_bf16.h>
#include <stdint.h>

// Problem constants
#define B_ 16
#define L_ 4096
#define D_ 256
#define M_ (B_*L_)   // 65536 tokens
#define N_ 768       // [loop | parent | child] concatenated output cols

typedef __attribute__((ext_vector_type(8))) short bf16x8;
typedef __attribute__((ext_vector_type(4))) float f32x4;
typedef __attribute__((ext_vector_type(4))) int i32x4;

__device__ __forceinline__ float bf2f(unsigned short u) {
  union { unsigned int i; float f; } v; v.i = ((unsigned int)u) << 16; return v.f;
}
__device__ __forceinline__ unsigned short f2bf(float f) {
  __hip_bfloat16 h = __float2bfloat16(f);
  return *reinterpret_cast<unsigned short*>(&h);
}
__device__ __forceinline__ void async16(const void* g, void* l) {
  __builtin_amdgcn_global_load_lds((const __attribute__((address_space(1))) void*)g,
                                   (__attribute__((address_space(3))) void*)l, 16, 0, 0);
}
__device__ __forceinline__ float sigmoidf_(float z) {
  return 1.f / (1.f + __expf(-z));
}

// ---------------------------------------------------------------------------
// Kernel A: per-token gate logits (f32 exact) + x -> bf16 conversion,
// fused with CSR child-count (dest>=1 destinations only).
// ---------------------------------------------------------------------------
__global__ __launch_bounds__(256) void k_gates(
    const float* __restrict__ x, const int* __restrict__ deps,
    const int* __restrict__ parent, const int* __restrict__ mask,
    const float* __restrict__ wlg, const float* __restrict__ blg,
    const float* __restrict__ wcg, const float* __restrict__ bcg,
    const float* __restrict__ wpg, const float* __restrict__ bpg,
    const float* __restrict__ Epg, const float* __restrict__ Ecg,
    unsigned short* __restrict__ xb, float4* __restrict__ gates,
    int* __restrict__ cnt)
{
  const int lane = threadIdx.x & 63;
  const int gw = (blockIdx.x * 256 + threadIdx.x) >> 6;  // global wave id
  const float4 wl4 = ((const float4*)wlg)[lane];
  const float4 wc4 = ((const float4*)wcg)[lane];
  const float4 wp4 = ((const float4*)wpg)[lane];
  const float bl0 = blg[0], bc0 = bcg[0], bp0 = bpg[0];
  for (int t = 0; t < 8; ++t) {
    const int i = gw * 8 + t;
    const int b = i >> 12;
    float4 xv = ((const float4*)x)[(size_t)i * 64 + lane];
    float sl = xv.x * wl4.x + xv.y * wl4.y + xv.z * wl4.z + xv.w * wl4.w;
    float sc = xv.x * wc4.x + xv.y * wc4.y + xv.z * wc4.z + xv.w * wc4.w;
    float sp = xv.x * wp4.x + xv.y * wp4.y + xv.z * wp4.z + xv.w * wp4.w;
    #pragma unroll
    for (int o = 32; o; o >>= 1) {
      sl += __shfl_xor(sl, o);
      sc += __shfl_xor(sc, o);
      sp += __shfl_xor(sp, o);
    }
    ushort4 u;
    u.x = f2bf(xv.x); u.y = f2bf(xv.y); u.z = f2bf(xv.z); u.w = f2bf(xv.w);
    ((ushort4*)xb)[(size_t)i * 64 + lane] = u;
    if (lane == 0) {
      int d = deps[i];
      float gl = sigmoidf_(sl + bl0);
      float gp = sigmoidf_(sp + bp0 + Epg[d]);
      float gc = sigmoidf_(sc + bc0 + Ecg[d]);
      gates[i] = make_float4(gl, gp, gc, 0.f);
      // CSR count: children with dest p>=1 whose destination row survives mask
      int mi = mask[i];
      if (mi) {
        int p = parent[i];
        if (p > 0 && mask[(b << 12) + p]) atomicAdd(&cnt[(b << 12) + p], 1);
      }
    }
  }
}

// ---------------------------------------------------------------------------
// Kernel W: WbT [768][256] bf16 = transpose of [W_loop|W_parent|W_child].
// ---------------------------------------------------------------------------
__global__ __launch_bounds__(256) void k_weights(
    const float* __restrict__ Wl, const float* __restrict__ Wp,
    const float* __restrict__ Wc, unsigned short* __restrict__ WbT)
{
  const int n = blockIdx.x;      // 0..767 output col
  const int k = threadIdx.x;     // 0..255
  const float* W = (n < 256) ? Wl : ((n < 512) ? Wp : Wc);
  const int nn = n & 255;
  WbT[(size_t)n * 256 + k] = f2bf(W[(size_t)k * 256 + nn]);
}

// ---------------------------------------------------------------------------
// Kernel S2: per-batch exclusive scan of cnt -> off, and cursor copy.
// One block (256 threads) per batch, 16 values/thread, LDS Hillis-Steele.
// ---------------------------------------------------------------------------
__global__ __launch_bounds__(256) void k_scan(
    const int* __restrict__ cnt, int* __restrict__ off, int* __restrict__ cur)
{
  const int b = blockIdx.x, t = threadIdx.x;
  const int base = (b << 12) + t * 16;
  int v, pre[16], s = 0;
  #pragma unroll
  for (int j = 0; j < 16; ++j) { v = cnt[base + j]; pre[j] = s; s += v; }
  __shared__ int tot[256];
  tot[t] = s;
  __syncthreads();
  for (int o = 1; o < 256; o <<= 1) {
    int x = (t >= o) ? tot[t - o] : 0;
    __syncthreads();
    tot[t] += x;
    __syncthreads();
  }
  const int bexc = tot[t] - s;   // exclusive prefix for this thread
  #pragma unroll
  for (int j = 0; j < 16; ++j) {
    off[base + j] = bexc + pre[j];
    cur[base + j] = bexc + pre[j];
  }
}

// ---------------------------------------------------------------------------
// Kernel S3: CSR fill. lists[(b<<12)+pos] = child token index.
// ---------------------------------------------------------------------------
__global__ __launch_bounds__(256) void k_fill(
    const int* __restrict__ parent, const int* __restrict__ mask,
    int* __restrict__ cur, int* __restrict__ lists)
{
  const int i = blockIdx.x * 256 + threadIdx.x;
  const int b = i >> 12;
  if (!mask[i]) return;
  const int p = parent[i];
  if (p == 0) return;
  if (!mask[(b << 12) + p]) return;
  const int pos = atomicAdd(&cur[(b << 12) + p], 1);  // batch-local, includes off
  lists[(b << 12) + pos] = i;
}

// ---------------------------------------------------------------------------
// Kernel B: Y[65536][768] (bf16) = xb @ Wb.  128x128 tile, 4 waves, BK=64,
// global_load_lds width-16 staging, mfma_f32_16x16x32_bf16.
// ---------------------------------------------------------------------------
__global__ __launch_bounds__(256) void k_gemm(
    const unsigned short* __restrict__ A,    // [M][256] bf16
    const unsigned short* __restrict__ Bt,   // [768][256] bf16 (N-major)
    unsigned short* __restrict__ Y)          // [M][768] bf16
{
  __shared__ unsigned short sh[2 * 128 * 64];
  unsigned short* lA = sh;
  unsigned short* lB = sh + 128 * 64;
  const int tid = threadIdx.x;
  const int wid = tid >> 6, lane = tid & 63;
  const int wm = wid >> 1, wn = wid & 1;
  const int mb = blockIdx.x, nb = blockIdx.y;

  f32x4 acc[4][4] = {};
  const unsigned short* Ag = A + (size_t)mb * 128 * 256;
  const unsigned short* Bg = Bt + (size_t)nb * 128 * 256;
  const int srow = wid * 8 + (lane >> 3);   // staging row within 32-row sweep
  const int scol = (lane & 7) * 8;          // staging col (bf16)

  for (int kb = 0; kb < 256; kb += 64) {
    #pragma unroll
    for (int s = 0; s < 4; ++s) {
      char* dA = (char*)lA + s * 4096 + wid * 1024 + lane * 16;
      char* dB = (char*)lB + s * 4096 + wid * 1024 + lane * 16;
      async16(Ag + (size_t)(s * 32 + srow) * 256 + kb + scol, dA);
      async16(Bg + (size_t)(s * 32 + srow) * 256 + kb + scol, dB);
    }
    __syncthreads();
    #pragma unroll
    for (int kk = 0; kk < 64; kk += 32) {
      const int ko = kk + (lane >> 4) * 8;
      bf16x8 af[4], bv[4];
      #pragma unroll
      for (int m = 0; m < 4; ++m)
        af[m] = *(const bf16x8*)&lA[(wm * 64 + m * 16 + (lane & 15)) * 64 + ko];
      #pragma unroll
      for (int n = 0; n < 4; ++n)
        bv[n] = *(const bf16x8*)&lB[(wn * 64 + n * 16 + (lane & 15)) * 64 + ko];
      #pragma unroll
      for (int m = 0; m < 4; ++m)
        #pragma unroll
        for (int n = 0; n < 4; ++n)
          acc[m][n] = __builtin_amdgcn_mfma_f32_16x16x32_bf16(af[m], bv[n], acc[m][n], 0, 0, 0);
    }
    __syncthreads();
  }

  // Epilogue: fragments -> LDS (bf16, [128][128]) -> coalesced 16B stores.
  #pragma unroll
  for (int m = 0; m < 4; ++m)
    #pragma unroll
    for (int n = 0; n < 4; ++n)
      #pragma unroll
      for (int r = 0; r < 4; ++r)
        sh[(wm * 64 + m * 16 + (lane >> 4) * 4 + r) * 128 + wn * 64 + n * 16 + (lane & 15)]
            = f2bf(acc[m][n][r]);
  __syncthreads();
  #pragma unroll
  for (int s = 0; s < 8; ++s) {
    const int o = s * 4096 + tid * 16;          // byte offset in 32KB tile
    const int row = o >> 8;                     // 256 B per row (128 bf16)
    const int colu = (o & 255) >> 1;            // bf16 col
    *(i32x4*)&Y[(size_t)(mb * 128 + row) * 768 + nb * 128 + colu] =
        *(const i32x4*)((const char*)sh + o);
  }
}

// ---------------------------------------------------------------------------
// Kernel F: fused combine + child gather. One wave per output row; writes
// each row exactly once (zeros if masked). No atomics.
// ---------------------------------------------------------------------------
__global__ __launch_bounds__(256) void k_fused(
    const unsigned short* __restrict__ Y, const float4* __restrict__ gates,
    const int* __restrict__ parent, const int* __restrict__ deps,
    const int* __restrict__ mask, const int* __restrict__ cnt,
    const int* __restrict__ off, const int* __restrict__ lists,
    const float* __restrict__ b_loop, const float* __restrict__ b_parent,
    const float* __restrict__ b_child,
    const float* __restrict__ Epw, const float* __restrict__ Ecw,
    float* __restrict__ out)
{
  const int lane = threadIdx.x & 63;
  const int i = blockIdx.x * 4 + (threadIdx.x >> 6);   // output row (token)
  const int b = i >> 12;
  float4* orow = (float4*)(out + (size_t)i * 256) + lane;
  if (!mask[i]) { *orow = make_float4(0.f, 0.f, 0.f, 0.f); return; }

  const float4 g = gates[i];
  const int p = parent[i], d = deps[i];
  const float4 bl = ((const float4*)b_loop)[lane];
  const float4 bp = ((const float4*)b_parent)[lane];
  const ushort4 yl = ((const ushort4*)(Y + (size_t)i * 768))[lane];
  const ushort4 z  = ((const ushort4*)(Y + (size_t)((b << 12) + p) * 768 + 256))[lane];
  const float4 e   = ((const float4*)Epw)[d * 64 + lane];
  float4 o;
  o.x = g.x * (bf2f(yl.x) + bl.x) + g.y * (bf2f(z.x) + bp.x + e.x);
  o.y = g.x * (bf2f(yl.y) + bl.y) + g.y * (bf2f(z.y) + bp.y + e.y);
  o.z = g.x * (bf2f(yl.z) + bl.z) + g.y * (bf2f(z.z) + bp.z + e.z);
  o.w = g.x * (bf2f(yl.w) + bl.w) + g.y * (bf2f(z.w) + bp.w + e.w);

  const int n = cnt[i];
  if (n) {
    const int o0 = off[i];
    const float4 bc = ((const float4*)b_child)[lane];
    for (int k = 0; k < n; ++k) {
      const int c = lists[(b << 12) + o0 + k];
      const float gc = ((const float*)gates)[c * 4 + 2];
      const int dc = deps[c];
      const ushort4 yc = ((const ushort4*)(Y + (size_t)c * 768 + 512))[lane];
      const float4 ec = ((const float4*)Ecw)[dc * 64 + lane];
      o.x += gc * (bf2f(yc.x) + bc.x + ec.x);
      o.y += gc * (bf2f(yc.y) + bc.y + ec.y);
      o.z += gc * (bf2f(yc.z) + bc.z + ec.z);
      o.w += gc * (bf2f(yc.w) + bc.w + ec.w);
    }
  }
  *orow = o;
}

// ---------------------------------------------------------------------------
// Kernel R0a: row-0 child reduction, stage 1. Block (b, slice of 64 tokens):
// register-accumulate contributions with dest==0, LDS-reduce 4 waves,
// write one float4[64] partial per block. No atomics.
// ---------------------------------------------------------------------------
__global__ __launch_bounds__(256) void k_row0a(
    const unsigned short* __restrict__ Y, const float4* __restrict__ gates,
    const int* __restrict__ parent, const int* __restrict__ deps,
    const int* __restrict__ mask, const float* __restrict__ b_child,
    const float* __restrict__ Ecw, float4* __restrict__ partial)
{
  const int blk = blockIdx.x;          // 0..1023
  const int b = blk >> 6;
  const int lane = threadIdx.x & 63;
  const int wid = threadIdx.x >> 6;
  float4 acc = make_float4(0.f, 0.f, 0.f, 0.f);
  if (mask[b << 12]) {
    const float4 bc = ((const float4*)b_child)[lane];
    const int tbase = (b << 12) + (blk & 63) * 64 + wid * 16;
    for (int t = 0; t < 16; ++t) {
      const int i = tbase + t;
      const int mi = mask[i];
      const int p = parent[i];
      if (mi && p != 0) continue;      // dest != 0
      const float gc = ((const float*)gates)[i * 4 + 2];
      const int d = deps[i];
      const ushort4 yc = ((const ushort4*)(Y + (size_t)i * 768 + 512))[lane];
      const float4 ec = ((const float4*)Ecw)[d * 64 + lane];
      acc.x += gc * (bf2f(yc.x) + bc.x + ec.x);
      acc.y += gc * (bf2f(yc.y) + bc.y + ec.y);
      acc.z += gc * (bf2f(yc.z) + bc.z + ec.z);
      acc.w += gc * (bf2f(yc.w) + bc.w + ec.w);
    }
  }
  __shared__ float4 red[4][64];
  red[wid][lane] = acc;
  __syncthreads();
  if (wid == 0) {
    float4 a0 = red[0][lane], a1 = red[1][lane], a2 = red[2][lane], a3 = red[3][lane];
    a0.x += a1.x + a2.x + a3.x;
    a0.y += a1.y + a2.y + a3.y;
    a0.z += a1.z + a2.z + a3.z;
    a0.w += a1.w + a2.w + a3.w;
    partial[blk * 64 + lane] = a0;
  }
}

// ---------------------------------------------------------------------------
// Kernel R0b: row-0 child reduction, stage 2. One small block per batch:
// sum the 64 partials and add into out row 0 (non-atomic; single writer).
// ---------------------------------------------------------------------------
__global__ __launch_bounds__(64) void k_row0b(
    const int* __restrict__ mask, const float4* __restrict__ partial,
    float* __restrict__ out)
{
  const int b = blockIdx.x;
  if (!mask[b << 12]) return;
  const int t = threadIdx.x;           // 0..63, one float4 column each
  float4 acc = make_float4(0.f, 0.f, 0.f, 0.f);
  for (int k = 0; k < 64; ++k) {
    const float4 v = partial[(b * 64 + k) * 64 + t];
    acc.x += v.x; acc.y += v.y; acc.z += v.z; acc.w += v.w;
  }
  float4* orow = (float4*)(out + (size_t)(b << 12) * 256) + t;
  float4 o = *orow;
  o.x += acc.x; o.y += acc.y; o.z += acc.z; o.w += acc.w;
  *orow = o;
}

// ---------------------------------------------------------------------------
extern "C" void kernel_launch(void* const* d_in, const int* in_sizes, int n_in,
                              void* d_out, int out_size, void* d_ws, size_t ws_size,
                              hipStream_t stream) {
  const float* x        = (const float*)d_in[0];
  const int*   parent   = (const int*)d_in[1];
  const int*   deps     = (const int*)d_in[2];
  const int*   mask     = (const int*)d_in[3];
  const float* W_loop   = (const float*)d_in[4];
  const float* b_loop   = (const float*)d_in[5];
  const float* W_child  = (const float*)d_in[6];
  const float* b_child  = (const float*)d_in[7];
  const float* W_parent = (const float*)d_in[8];
  const float* b_parent = (const float*)d_in[9];
  const float* wlg      = (const float*)d_in[10];
  const float* blg      = (const float*)d_in[11];
  const float* wcg      = (const float*)d_in[12];
  const float* bcg      = (const float*)d_in[13];
  const float* wpg      = (const float*)d_in[14];
  const float* bpg      = (const float*)d_in[15];
  const float* Epw      = (const float*)d_in[16];
  const float* Ecw      = (const float*)d_in[17];
  const float* Epg      = (const float*)d_in[18];
  const float* Ecg      = (const float*)d_in[19];
  float* out = (float*)d_out;

  // Workspace layout (~130.4 MB). partial aliases xb (xb dead after gemm).
  char* ws = (char*)d_ws;
  unsigned short* xb  = (unsigned short*)ws;                         // 32 MB
  float4* partial     = (float4*)ws;                                 // 1 MB (alias, post-gemm)
  unsigned short* WbT = (unsigned short*)(ws + 33554432);            // 384 KB
  float4* gates       = (float4*)(ws + 33947648);                    // 1 MB
  unsigned short* Yv  = (unsigned short*)(ws + 34996224);            // 96 MB
  int* cnt            = (int*)(ws + 135659520);                      // 256 KB
  int* off            = (int*)(ws + 135921664);                      // 256 KB
  int* cur            = (int*)(ws + 136183808);                      // 256 KB
  int* lists          = (int*)(ws + 136445952);                      // 256 KB

  hipMemsetAsync(cnt, 0, 262144, stream);
  k_gates<<<2048, 256, 0, stream>>>(x, deps, parent, mask, wlg, blg, wcg, bcg,
                                    wpg, bpg, Epg, Ecg, xb, gates, cnt);
  k_weights<<<768, 256, 0, stream>>>(W_loop, W_parent, W_child, WbT);
  k_scan<<<16, 256, 0, stream>>>(cnt, off, cur);
  k_fill<<<256, 256, 0, stream>>>(parent, mask, cur, lists);
  dim3 gg(512, 6, 1);
  k_gemm<<<gg, 256, 0, stream>>>(xb, WbT, Yv);
  k_row0a<<<1024, 256, 0, stream>>>(Yv, gates, parent, deps, mask, b_child,
                                    Ecw, partial);
  k_fused<<<16384, 256, 0, stream>>>(Yv, gates, parent, deps, mask, cnt, off,
                                     lists, b_loop, b_parent, b_child,
                                     Epw, Ecw, out);
  k_row0b<<<16, 64, 0, stream>>>(mask, partial, out);
}